// Round 13
// baseline (147.100 us; speedup 1.0000x reference)
//
#include <hip/hip_runtime.h>

typedef __attribute__((ext_vector_type(8))) short short8;
typedef __attribute__((ext_vector_type(4))) float f32x4;
typedef __attribute__((ext_vector_type(2))) float f32x2;
typedef __attribute__((ext_vector_type(4))) unsigned int u32x4;

static __device__ __forceinline__ unsigned int fbits(float f) {
    union { float f; unsigned int u; } v; v.f = f; return v.u;
}
static __device__ __forceinline__ float bitsf(unsigned int u) {
    union { float f; unsigned int u; } v; v.u = u; return v.f;
}
// pack two f32 -> bf16 pair in ONE VALU op (v_perm_b32 byte select)
static __device__ __forceinline__ unsigned int pkbf(float lo, float hi) {
    return __builtin_amdgcn_perm(fbits(hi), fbits(lo), 0x07060302u);
}
static __device__ __forceinline__ float leaky(float x) { return fmaxf(x, 0.01f * x); }
static __device__ __forceinline__ float rsqrt_nr(float x) {
    const float r = __builtin_amdgcn_rsqf(x);
    return r * (1.5f - (0.5f * x) * (r * r));
}
static __device__ __forceinline__ f32x2 pk_mul_v(f32x2 a, f32x2 b) {
    f32x2 d; asm("v_pk_mul_f32 %0, %1, %2" : "=v"(d) : "v"(a), "v"(b)); return d;
}
static __device__ __forceinline__ f32x2 pk_fma_v(f32x2 a, f32x2 b, f32x2 c) {
    f32x2 d; asm("v_pk_fma_f32 %0, %1, %2, %3" : "=v"(d) : "v"(a), "v"(b), "v"(c)); return d;
}

// ROUND 12 kernel, resubmitted (r12 bench was GPUAcquisitionTimeout -- infra;
// kernel never measured).
// ALL FOUR LAYERS ON MFMA -- zero weight streaming in the per-row path.
// Evidence: wall pinned 53-59us across r0-r11 while falsifying occupancy (r4/r5),
// CP dispatch (r6), barrier rendezvous (r9), wave count (r11). Issue arithmetic
// says ~4 CU-cyc/row; measured ~16 -- a serial unmodeled cost. The one structure
// identical in EVERY round: gs_l1's 128 wave-uniform gW1/gb1 loads inside the
// per-row path (112 SGPRs can't hold them -> batched s_load + lgkmcnt waits,
// serialized in every wave's pre-barrier ramp).
// Fix: L1 joins the verified swapped-operand MFMA chain (r10 algebra, absmax
// 4.77e-7): z1^T = mfma(A=W1 zero-padded K 3->32, B=feat^T). All weights live in
// VGPR fragments loaded once in the preamble; biases are MFMA C operands. The
// pre-barrier ramp shrinks to GS + feat-pack (~50 ops).
//
// feat LDS: stride 8 u32 (32 B). Row r, u32 j = bf16 pair (k=j lo, k=j+16 hi):
// j<3 lo = feat[j], everything else 0. Lanes read b128 at +4*quad: quad0 = feat;
// quad1 = zeros; quad2/3 = next row's words (finite garbage/zeros) -- all k>=3
// slots multiply ZERO A-weights, so any finite B value is annihilated. Pad row
// 256 zeroed for the t=3/i15=15 overread. 4-way b128 bank conflict on one read
// per tile (stride-8 pattern) -- negligible at this count.
//
// C-layout algebra (verified r10): acc{lo,hi}[r] = z[16t+(i15)][{4q+r, 4q+r+16}]
// == the next layer's B-fragment slot set -> leaky/gate/pkbf chain in registers.
// L4 stays per-lane pk-dot + butterfly shfl_xor(16,32); lane keeps tile t==quad.

__global__ __launch_bounds__(256, 4) void aero_mfma(
    const float* __restrict__ vin, const float* __restrict__ win,
    const float* __restrict__ gW1, const float* __restrict__ gb1,
    const float* __restrict__ gW2, const float* __restrict__ gb2,
    const float* __restrict__ gWd1, const float* __restrict__ gbd1,
    const float* __restrict__ gWd2, const float* __restrict__ gbd2,
    const float* __restrict__ gbias,
    float* __restrict__ out, int nrows)
{
    __shared__ unsigned int featlds[257 * 8];   // 32 B row stride + 1 pad row

    const int tid   = threadIdx.x;
    const int i15   = tid & 15;
    const int quad  = (tid >> 4) & 3;
    const int wbase = tid & 192;               // wave's 64-row window
    const int ko    = 4 * quad;

    int row = blockIdx.x * 256 + tid;
    if (row >= nrows) row = nrows - 1;         // benign duplicate work

    // ---- preamble: ALL weights -> VGPR fragments (once per wave) ----
    // W1 A-frag: lane (i15,q) holds W1[m][k in {ko+j, ko+j+16}]; k valid only <3.
    unsigned int a1lo[4] = {0,0,0,0}, a1hi[4] = {0,0,0,0};
    if (quad == 0) {
        #pragma unroll
        for (int j = 0; j < 3; ++j) {
            a1lo[j] = fbits(gW1[i15 * 3 + j]) >> 16;          // (W1, 0) pair
            a1hi[j] = fbits(gW1[(16 + i15) * 3 + j]) >> 16;
        }
    }
    const short8 fW1lo = __builtin_bit_cast(short8, (u32x4){a1lo[0], a1lo[1], a1lo[2], a1lo[3]});
    const short8 fW1hi = __builtin_bit_cast(short8, (u32x4){a1hi[0], a1hi[1], a1hi[2], a1hi[3]});

    unsigned int a2lo[4], a2hi[4], a3lo[4], a3hi[4];
    {
        const float* p;
        p = gW2 + i15 * 32 + ko;
        { f32x4 xa = *(const f32x4*)p, xb = *(const f32x4*)(p + 16);
          #pragma unroll
          for (int j = 0; j < 4; ++j) a2lo[j] = pkbf(xa[j], xb[j]); }
        p = gW2 + (16 + i15) * 32 + ko;
        { f32x4 xa = *(const f32x4*)p, xb = *(const f32x4*)(p + 16);
          #pragma unroll
          for (int j = 0; j < 4; ++j) a2hi[j] = pkbf(xa[j], xb[j]); }
        p = gWd1 + i15 * 32 + ko;
        { f32x4 xa = *(const f32x4*)p, xb = *(const f32x4*)(p + 16);
          #pragma unroll
          for (int j = 0; j < 4; ++j) a3lo[j] = pkbf(xa[j], xb[j]); }
        p = gWd1 + (16 + i15) * 32 + ko;
        { f32x4 xa = *(const f32x4*)p, xb = *(const f32x4*)(p + 16);
          #pragma unroll
          for (int j = 0; j < 4; ++j) a3hi[j] = pkbf(xa[j], xb[j]); }
    }
    const short8 fW2lo  = __builtin_bit_cast(short8, (u32x4){a2lo[0], a2lo[1], a2lo[2], a2lo[3]});
    const short8 fW2hi  = __builtin_bit_cast(short8, (u32x4){a2hi[0], a2hi[1], a2hi[2], a2hi[3]});
    const short8 fWd1lo = __builtin_bit_cast(short8, (u32x4){a3lo[0], a3lo[1], a3lo[2], a3lo[3]});
    const short8 fWd1hi = __builtin_bit_cast(short8, (u32x4){a3hi[0], a3hi[1], a3hi[2], a3hi[3]});

    // Wd2 pairs, named (no runtime-indexed arrays -> no scratch)
    f32x2 w00, w01, w02, w03, w10, w11, w12, w13, w20, w21, w22, w23;
    {
        f32x4 xa, xb;
        xa = *(const f32x4*)(gWd2 + 0*32 + ko); xb = *(const f32x4*)(gWd2 + 0*32 + ko + 16);
        w00.x = xa[0]; w00.y = xb[0]; w01.x = xa[1]; w01.y = xb[1];
        w02.x = xa[2]; w02.y = xb[2]; w03.x = xa[3]; w03.y = xb[3];
        xa = *(const f32x4*)(gWd2 + 1*32 + ko); xb = *(const f32x4*)(gWd2 + 1*32 + ko + 16);
        w10.x = xa[0]; w10.y = xb[0]; w11.x = xa[1]; w11.y = xb[1];
        w12.x = xa[2]; w12.y = xb[2]; w13.x = xa[3]; w13.y = xb[3];
        xa = *(const f32x4*)(gWd2 + 2*32 + ko); xb = *(const f32x4*)(gWd2 + 2*32 + ko + 16);
        w20.x = xa[0]; w20.y = xb[0]; w21.x = xa[1]; w21.y = xb[1];
        w22.x = xa[2]; w22.y = xb[2]; w23.x = xa[3]; w23.y = xb[3];
    }
    // bias C-operands: acc[r] init = b[ko+r] / b[16+ko+r]
    const f32x4 cb1lo  = *(const f32x4*)(gb1  + ko);
    const f32x4 cb1hi  = *(const f32x4*)(gb1  + 16 + ko);
    const f32x4 cb2lo  = *(const f32x4*)(gb2  + ko);
    const f32x4 cb2hi  = *(const f32x4*)(gb2  + 16 + ko);
    const f32x4 cbd1lo = *(const f32x4*)(gbd1 + ko);
    const f32x4 cbd1hi = *(const f32x4*)(gbd1 + 16 + ko);

    // ---- Gram-Schmidt + feat (the ONLY pre-barrier per-row work) ----
    const float v0 = vin[3*row+0], v1 = vin[3*row+1], v2 = vin[3*row+2];
    const float w0 = win[3*row+0], w1 = win[3*row+1], w2 = win[3*row+2];

    const float sv  = v0*v0 + v1*v1 + v2*v2;
    const float rnv = rsqrt_nr(sv);
    const float a0 = v0*rnv, a1 = v1*rnv, a2 = v2*rnv;            // v_on
    const float proj = w0*a0 + w1*a1 + w2*a2;
    const float o0 = w0 - proj*a0, o1 = w1 - proj*a1, o2 = w2 - proj*a2;
    const float sw  = o0*o0 + o1*o1 + o2*o2;
    const float rnw = rsqrt_nr(sw);
    const float c0 = o0*rnw, c1 = o1*rnw, c2 = o2*rnw;            // w_on
    const float u0 = a1*c2 - a2*c1;                               // u_on
    const float u1 = a2*c0 - a0*c2;
    const float u2 = a0*c1 - a1*c0;

    const float f0 = sv*rnv, f1 = proj, f2 = sw*rnw;

    // feat row: u32 j = (k=j lo, k=j+16 hi); only j<3 lo nonzero
    *(u32x4*)(&featlds[tid * 8])     = (u32x4){ fbits(f0) >> 16, fbits(f1) >> 16,
                                                fbits(f2) >> 16, 0u };
    *(u32x4*)(&featlds[tid * 8 + 4]) = (u32x4){ 0u, 0u, 0u, 0u };
    if (tid < 8) featlds[256 * 8 + tid] = 0u;   // pad row for the quad2/3 overread
    __syncthreads();

    // ---- fused layers 1..4, all weights/activations in registers ----
    float y0 = 0.f, y1 = 0.f, y2 = 0.f;
    #pragma unroll
    for (int t = 0; t < 4; ++t) {
        // feat B-frag (quad>0 slots hit zero A-weights -> value irrelevant, finite)
        const u32x4 bfr = *(const u32x4*)(&featlds[(wbase + 16*t + i15) * 8 + ko]);
        const short8 featfrag = __builtin_bit_cast(short8, bfr);

        // L1: z1[row][{ko+r, ko+r+16}]
        const f32x4 z1lo = __builtin_amdgcn_mfma_f32_16x16x32_bf16(fW1lo, featfrag, cb1lo, 0, 0, 0);
        const f32x4 z1hi = __builtin_amdgcn_mfma_f32_16x16x32_bf16(fW1hi, featfrag, cb1hi, 0, 0, 0);
        float h1l0 = leaky(z1lo[0]), h1l1 = leaky(z1lo[1]), h1l2 = leaky(z1lo[2]), h1l3 = leaky(z1lo[3]);
        float h1h0 = leaky(z1hi[0]), h1h1 = leaky(z1hi[1]), h1h2 = leaky(z1hi[2]), h1h3 = leaky(z1hi[3]);
        const short8 h1frag = __builtin_bit_cast(short8,
            (u32x4){ pkbf(h1l0, h1h0), pkbf(h1l1, h1h1), pkbf(h1l2, h1h2), pkbf(h1l3, h1h3) });

        // L2 + gate (gate operand = the f32 h1 values already in hand)
        const f32x4 z2lo = __builtin_amdgcn_mfma_f32_16x16x32_bf16(fW2lo, h1frag, cb2lo, 0, 0, 0);
        const f32x4 z2hi = __builtin_amdgcn_mfma_f32_16x16x32_bf16(fW2hi, h1frag, cb2hi, 0, 0, 0);
        const short8 h2frag = __builtin_bit_cast(short8, (u32x4){
            pkbf(leaky(z2lo[0]) * h1l0, leaky(z2hi[0]) * h1h0),
            pkbf(leaky(z2lo[1]) * h1l1, leaky(z2hi[1]) * h1h1),
            pkbf(leaky(z2lo[2]) * h1l2, leaky(z2hi[2]) * h1h2),
            pkbf(leaky(z2lo[3]) * h1l3, leaky(z2hi[3]) * h1h3) });

        // L3 (f32 accum stays f32 into L4)
        const f32x4 z3lo = __builtin_amdgcn_mfma_f32_16x16x32_bf16(fWd1lo, h2frag, cbd1lo, 0, 0, 0);
        const f32x4 z3hi = __builtin_amdgcn_mfma_f32_16x16x32_bf16(fWd1hi, h2frag, cbd1hi, 0, 0, 0);
        f32x2 h30, h31, h32, h33;
        h30.x = leaky(z3lo[0]); h30.y = leaky(z3hi[0]);
        h31.x = leaky(z3lo[1]); h31.y = leaky(z3hi[1]);
        h32.x = leaky(z3lo[2]); h32.y = leaky(z3hi[2]);
        h33.x = leaky(z3lo[3]); h33.y = leaky(z3hi[3]);

        // L4: per-lane pk-dot over this lane's 8 features + butterfly over q-lanes
        f32x2 P0 = pk_mul_v(w00, h30);
        f32x2 P1 = pk_mul_v(w10, h30);
        f32x2 P2 = pk_mul_v(w20, h30);
        P0 = pk_fma_v(w01, h31, P0); P1 = pk_fma_v(w11, h31, P1); P2 = pk_fma_v(w21, h31, P2);
        P0 = pk_fma_v(w02, h32, P0); P1 = pk_fma_v(w12, h32, P1); P2 = pk_fma_v(w22, h32, P2);
        P0 = pk_fma_v(w03, h33, P0); P1 = pk_fma_v(w13, h33, P1); P2 = pk_fma_v(w23, h33, P2);
        float s0 = P0.x + P0.y, s1 = P1.x + P1.y, s2 = P2.x + P2.y;
        s0 += __shfl_xor(s0, 16); s0 += __shfl_xor(s0, 32);
        s1 += __shfl_xor(s1, 16); s1 += __shfl_xor(s1, 32);
        s2 += __shfl_xor(s2, 16); s2 += __shfl_xor(s2, 32);
        if (quad == t) { y0 = s0; y1 = s1; y2 = s2; }   // 16t+i15 == this lane's row
    }
    y0 += gbd2[0]; y1 += gbd2[1]; y2 += gbd2[2];

    // ---- rotate by R = [v_on | w_on | u_on], add bias, store ----
    out[3*row + 0] = fmaf(a0, y0, fmaf(c0, y1, fmaf(u0, y2, gbias[0])));
    out[3*row + 1] = fmaf(a1, y0, fmaf(c1, y1, fmaf(u1, y2, gbias[1])));
    out[3*row + 2] = fmaf(a2, y0, fmaf(c2, y1, fmaf(u2, y2, gbias[2])));
}

extern "C" void kernel_launch(void* const* d_in, const int* in_sizes, int n_in,
                              void* d_out, int out_size, void* d_ws, size_t ws_size,
                              hipStream_t stream) {
    const float* v    = (const float*)d_in[0];
    const float* w    = (const float*)d_in[1];
    const float* W1   = (const float*)d_in[2];
    const float* b1   = (const float*)d_in[3];
    const float* W2   = (const float*)d_in[4];
    const float* b2   = (const float*)d_in[5];
    const float* Wd1  = (const float*)d_in[6];
    const float* bd1  = (const float*)d_in[7];
    const float* Wd2  = (const float*)d_in[8];
    const float* bd2  = (const float*)d_in[9];
    const float* bias = (const float*)d_in[10];

    const int nrows = in_sizes[0] / 3;
    dim3 block(256);
    dim3 grid((nrows + 255) / 256);
    hipLaunchKernelGGL(aero_mfma, grid, block, 0, stream,
                       v, w, W1, b1, W2, b2, Wd1, bd1, Wd2, bd2, bias,
                       (float*)d_out, nrows);
}

// Round 14
// 136.775 us; speedup vs baseline: 1.0755x; 1.0755x over previous
//
#include <hip/hip_runtime.h>

typedef __attribute__((ext_vector_type(8))) short short8;
typedef __attribute__((ext_vector_type(4))) float f32x4;
typedef __attribute__((ext_vector_type(2))) float f32x2;
typedef __attribute__((ext_vector_type(4))) unsigned int u32x4;

static __device__ __forceinline__ unsigned int fbits(float f) {
    union { float f; unsigned int u; } v; v.f = f; return v.u;
}
static __device__ __forceinline__ float bitsf(unsigned int u) {
    union { float f; unsigned int u; } v; v.u = u; return v.f;
}
static __device__ __forceinline__ unsigned int pkbf(float lo, float hi) {
    return __builtin_amdgcn_perm(fbits(hi), fbits(lo), 0x07060302u);
}
static __device__ __forceinline__ float leaky(float x) { return fmaxf(x, 0.01f * x); }
static __device__ __forceinline__ float rsqrt_nr(float x) {
    const float r = __builtin_amdgcn_rsqf(x);
    return r * (1.5f - (0.5f * x) * (r * r));
}
static __device__ __forceinline__ f32x2 pk_mul_v(f32x2 a, f32x2 b) {
    f32x2 d; asm("v_pk_mul_f32 %0, %1, %2" : "=v"(d) : "v"(a), "v"(b)); return d;
}
static __device__ __forceinline__ f32x2 pk_fma_v(f32x2 a, f32x2 b, f32x2 c) {
    f32x2 d; asm("v_pk_fma_f32 %0, %1, %2, %3" : "=v"(d) : "v"(a), "v"(b), "v"(c)); return d;
}

// ROUND 14: r13 (all-MFMA, no weight streaming -- session-low 32us VALU busy)
// + 2 ROWS/LANE. r13 proved the serial L1->L2->L3->L4 MFMA chain is exposed at
// ~2.8 waves/SIMD (wall 59 despite least issued work). 8 independent tile-chains
// per wave (vs 4) + preamble (~40 VMEM) amortized 2x. r11's null on this lever
// was confounded: its row-sets each carried gs_l1's serial SMEM ramp, which r13
// eliminated. If this is flat (53-59), the structural search is exhausted.
//
// Geometry: block=256 threads, 512 rows (sets A: rows base+tid, B: base+256+tid).
// featlds 513 rows x 32B. Set A tile reads can overrun into set B row 0 (quad2/3
// b128 overread) and set B into the zeroed pad row 512 -- all finite, and every
// k>=3 slot multiplies a ZERO A-weight (annihilated). C-layout algebra and row
// ownership (lane keeps tile t==quad; wbase+16t+i15==tid) verified r10-r13,
// absmax 4.77e-7 in every passing round.

struct Rot { float a0,a1,a2,c0,c1,c2,u0,u1,u2; };

static __device__ __forceinline__ Rot gs_feat(
    const float* __restrict__ vin, const float* __restrict__ win,
    int row, unsigned int* __restrict__ dst)
{
    const float v0 = vin[3*row+0], v1 = vin[3*row+1], v2 = vin[3*row+2];
    const float w0 = win[3*row+0], w1 = win[3*row+1], w2 = win[3*row+2];
    const float sv  = v0*v0 + v1*v1 + v2*v2;
    const float rnv = rsqrt_nr(sv);
    const float a0 = v0*rnv, a1 = v1*rnv, a2 = v2*rnv;            // v_on
    const float proj = w0*a0 + w1*a1 + w2*a2;
    const float o0 = w0 - proj*a0, o1 = w1 - proj*a1, o2 = w2 - proj*a2;
    const float sw  = o0*o0 + o1*o1 + o2*o2;
    const float rnw = rsqrt_nr(sw);
    const float c0 = o0*rnw, c1 = o1*rnw, c2 = o2*rnw;            // w_on
    const float u0 = a1*c2 - a2*c1;                               // u_on
    const float u1 = a2*c0 - a0*c2;
    const float u2 = a0*c1 - a1*c0;
    // feat row: u32 j = (k=j lo, k=j+16 hi); only j<3 lo nonzero
    *(u32x4*)(dst)     = (u32x4){ fbits(sv*rnv) >> 16, fbits(proj) >> 16,
                                  fbits(sw*rnw) >> 16, 0u };
    *(u32x4*)(dst + 4) = (u32x4){ 0u, 0u, 0u, 0u };
    return {a0,a1,a2,c0,c1,c2,u0,u1,u2};
}

// One 256-row set's fused L1..L4 chain. Uses enclosing scope: featlds, wbase,
// i15, quad, ko, fW1lo/hi, fW2lo/hi, fWd1lo/hi, cb*, w00..w23.
#define TILE_CHAIN(LB, YS0, YS1, YS2)                                              \
    {                                                                              \
        float y0k = 0.f, y1k = 0.f, y2k = 0.f;                                     \
        _Pragma("unroll")                                                          \
        for (int t = 0; t < 4; ++t) {                                              \
            const u32x4 bfr = *(const u32x4*)(                                     \
                &featlds[((LB) + wbase + 16*t + i15) * 8 + ko]);                   \
            const short8 featfrag = __builtin_bit_cast(short8, bfr);               \
            const f32x4 z1lo = __builtin_amdgcn_mfma_f32_16x16x32_bf16(            \
                fW1lo, featfrag, cb1lo, 0, 0, 0);                                  \
            const f32x4 z1hi = __builtin_amdgcn_mfma_f32_16x16x32_bf16(            \
                fW1hi, featfrag, cb1hi, 0, 0, 0);                                  \
            const float h1l0 = leaky(z1lo[0]), h1l1 = leaky(z1lo[1]);              \
            const float h1l2 = leaky(z1lo[2]), h1l3 = leaky(z1lo[3]);              \
            const float h1h0 = leaky(z1hi[0]), h1h1 = leaky(z1hi[1]);              \
            const float h1h2 = leaky(z1hi[2]), h1h3 = leaky(z1hi[3]);              \
            const short8 h1frag = __builtin_bit_cast(short8, (u32x4){              \
                pkbf(h1l0, h1h0), pkbf(h1l1, h1h1),                                \
                pkbf(h1l2, h1h2), pkbf(h1l3, h1h3) });                             \
            const f32x4 z2lo = __builtin_amdgcn_mfma_f32_16x16x32_bf16(            \
                fW2lo, h1frag, cb2lo, 0, 0, 0);                                    \
            const f32x4 z2hi = __builtin_amdgcn_mfma_f32_16x16x32_bf16(            \
                fW2hi, h1frag, cb2hi, 0, 0, 0);                                    \
            const short8 h2frag = __builtin_bit_cast(short8, (u32x4){              \
                pkbf(leaky(z2lo[0]) * h1l0, leaky(z2hi[0]) * h1h0),                \
                pkbf(leaky(z2lo[1]) * h1l1, leaky(z2hi[1]) * h1h1),                \
                pkbf(leaky(z2lo[2]) * h1l2, leaky(z2hi[2]) * h1h2),                \
                pkbf(leaky(z2lo[3]) * h1l3, leaky(z2hi[3]) * h1h3) });             \
            const f32x4 z3lo = __builtin_amdgcn_mfma_f32_16x16x32_bf16(            \
                fWd1lo, h2frag, cbd1lo, 0, 0, 0);                                  \
            const f32x4 z3hi = __builtin_amdgcn_mfma_f32_16x16x32_bf16(            \
                fWd1hi, h2frag, cbd1hi, 0, 0, 0);                                  \
            f32x2 h30, h31, h32, h33;                                              \
            h30.x = leaky(z3lo[0]); h30.y = leaky(z3hi[0]);                        \
            h31.x = leaky(z3lo[1]); h31.y = leaky(z3hi[1]);                        \
            h32.x = leaky(z3lo[2]); h32.y = leaky(z3hi[2]);                        \
            h33.x = leaky(z3lo[3]); h33.y = leaky(z3hi[3]);                        \
            f32x2 P0 = pk_mul_v(w00, h30);                                         \
            f32x2 P1 = pk_mul_v(w10, h30);                                         \
            f32x2 P2 = pk_mul_v(w20, h30);                                         \
            P0 = pk_fma_v(w01, h31, P0); P1 = pk_fma_v(w11, h31, P1);              \
            P2 = pk_fma_v(w21, h31, P2);                                           \
            P0 = pk_fma_v(w02, h32, P0); P1 = pk_fma_v(w12, h32, P1);              \
            P2 = pk_fma_v(w22, h32, P2);                                           \
            P0 = pk_fma_v(w03, h33, P0); P1 = pk_fma_v(w13, h33, P1);              \
            P2 = pk_fma_v(w23, h33, P2);                                           \
            float s0 = P0.x + P0.y, s1 = P1.x + P1.y, s2 = P2.x + P2.y;            \
            s0 += __shfl_xor(s0, 16); s0 += __shfl_xor(s0, 32);                    \
            s1 += __shfl_xor(s1, 16); s1 += __shfl_xor(s1, 32);                    \
            s2 += __shfl_xor(s2, 16); s2 += __shfl_xor(s2, 32);                    \
            if (quad == t) { y0k = s0; y1k = s1; y2k = s2; }                       \
        }                                                                          \
        YS0 = y0k; YS1 = y1k; YS2 = y2k;                                           \
    }

__global__ __launch_bounds__(256, 3) void aero_mfma(
    const float* __restrict__ vin, const float* __restrict__ win,
    const float* __restrict__ gW1, const float* __restrict__ gb1,
    const float* __restrict__ gW2, const float* __restrict__ gb2,
    const float* __restrict__ gWd1, const float* __restrict__ gbd1,
    const float* __restrict__ gWd2, const float* __restrict__ gbd2,
    const float* __restrict__ gbias,
    float* __restrict__ out, int nrows)
{
    __shared__ unsigned int featlds[513 * 8];   // 512 rows + 1 zero pad row

    const int tid   = threadIdx.x;
    const int i15   = tid & 15;
    const int quad  = (tid >> 4) & 3;
    const int wbase = tid & 192;               // wave's 64-row window (within a set)
    const int ko    = 4 * quad;

    const int base = blockIdx.x * 512;
    int rowA = base + tid;        if (rowA >= nrows) rowA = nrows - 1;
    int rowB = base + 256 + tid;  if (rowB >= nrows) rowB = nrows - 1;

    // ---- preamble (once per wave, amortized over 2 rows/lane) ----
    unsigned int a1lo[4] = {0,0,0,0}, a1hi[4] = {0,0,0,0};
    if (quad == 0) {
        #pragma unroll
        for (int j = 0; j < 3; ++j) {
            a1lo[j] = fbits(gW1[i15 * 3 + j]) >> 16;          // (W1, 0) pair
            a1hi[j] = fbits(gW1[(16 + i15) * 3 + j]) >> 16;
        }
    }
    const short8 fW1lo = __builtin_bit_cast(short8, (u32x4){a1lo[0], a1lo[1], a1lo[2], a1lo[3]});
    const short8 fW1hi = __builtin_bit_cast(short8, (u32x4){a1hi[0], a1hi[1], a1hi[2], a1hi[3]});

    unsigned int a2lo[4], a2hi[4], a3lo[4], a3hi[4];
    {
        const float* p;
        p = gW2 + i15 * 32 + ko;
        { f32x4 xa = *(const f32x4*)p, xb = *(const f32x4*)(p + 16);
          #pragma unroll
          for (int j = 0; j < 4; ++j) a2lo[j] = pkbf(xa[j], xb[j]); }
        p = gW2 + (16 + i15) * 32 + ko;
        { f32x4 xa = *(const f32x4*)p, xb = *(const f32x4*)(p + 16);
          #pragma unroll
          for (int j = 0; j < 4; ++j) a2hi[j] = pkbf(xa[j], xb[j]); }
        p = gWd1 + i15 * 32 + ko;
        { f32x4 xa = *(const f32x4*)p, xb = *(const f32x4*)(p + 16);
          #pragma unroll
          for (int j = 0; j < 4; ++j) a3lo[j] = pkbf(xa[j], xb[j]); }
        p = gWd1 + (16 + i15) * 32 + ko;
        { f32x4 xa = *(const f32x4*)p, xb = *(const f32x4*)(p + 16);
          #pragma unroll
          for (int j = 0; j < 4; ++j) a3hi[j] = pkbf(xa[j], xb[j]); }
    }
    const short8 fW2lo  = __builtin_bit_cast(short8, (u32x4){a2lo[0], a2lo[1], a2lo[2], a2lo[3]});
    const short8 fW2hi  = __builtin_bit_cast(short8, (u32x4){a2hi[0], a2hi[1], a2hi[2], a2hi[3]});
    const short8 fWd1lo = __builtin_bit_cast(short8, (u32x4){a3lo[0], a3lo[1], a3lo[2], a3lo[3]});
    const short8 fWd1hi = __builtin_bit_cast(short8, (u32x4){a3hi[0], a3hi[1], a3hi[2], a3hi[3]});

    f32x2 w00, w01, w02, w03, w10, w11, w12, w13, w20, w21, w22, w23;
    {
        f32x4 xa, xb;
        xa = *(const f32x4*)(gWd2 + 0*32 + ko); xb = *(const f32x4*)(gWd2 + 0*32 + ko + 16);
        w00.x = xa[0]; w00.y = xb[0]; w01.x = xa[1]; w01.y = xb[1];
        w02.x = xa[2]; w02.y = xb[2]; w03.x = xa[3]; w03.y = xb[3];
        xa = *(const f32x4*)(gWd2 + 1*32 + ko); xb = *(const f32x4*)(gWd2 + 1*32 + ko + 16);
        w10.x = xa[0]; w10.y = xb[0]; w11.x = xa[1]; w11.y = xb[1];
        w12.x = xa[2]; w12.y = xb[2]; w13.x = xa[3]; w13.y = xb[3];
        xa = *(const f32x4*)(gWd2 + 2*32 + ko); xb = *(const f32x4*)(gWd2 + 2*32 + ko + 16);
        w20.x = xa[0]; w20.y = xb[0]; w21.x = xa[1]; w21.y = xb[1];
        w22.x = xa[2]; w22.y = xb[2]; w23.x = xa[3]; w23.y = xb[3];
    }
    const f32x4 cb1lo  = *(const f32x4*)(gb1  + ko);
    const f32x4 cb1hi  = *(const f32x4*)(gb1  + 16 + ko);
    const f32x4 cb2lo  = *(const f32x4*)(gb2  + ko);
    const f32x4 cb2hi  = *(const f32x4*)(gb2  + 16 + ko);
    const f32x4 cbd1lo = *(const f32x4*)(gbd1 + ko);
    const f32x4 cbd1hi = *(const f32x4*)(gbd1 + 16 + ko);

    // ---- GS + feat for both rows (independent), one barrier ----
    const Rot RA = gs_feat(vin, win, rowA, &featlds[tid * 8]);
    const Rot RB = gs_feat(vin, win, rowB, &featlds[(256 + tid) * 8]);
    if (tid < 8) featlds[512 * 8 + tid] = 0u;   // pad row for set-B overread
    __syncthreads();

    // ---- 8 independent tile-chains (2 sets x 4 tiles), all in registers ----
    float yA0, yA1, yA2, yB0, yB1, yB2;
    TILE_CHAIN(0,   yA0, yA1, yA2);
    TILE_CHAIN(256, yB0, yB1, yB2);

    const float bd20 = gbd2[0], bd21 = gbd2[1], bd22 = gbd2[2];
    const float gbs0 = gbias[0], gbs1 = gbias[1], gbs2 = gbias[2];
    yA0 += bd20; yA1 += bd21; yA2 += bd22;
    yB0 += bd20; yB1 += bd21; yB2 += bd22;

    out[3*rowA + 0] = fmaf(RA.a0, yA0, fmaf(RA.c0, yA1, fmaf(RA.u0, yA2, gbs0)));
    out[3*rowA + 1] = fmaf(RA.a1, yA0, fmaf(RA.c1, yA1, fmaf(RA.u1, yA2, gbs1)));
    out[3*rowA + 2] = fmaf(RA.a2, yA0, fmaf(RA.c2, yA1, fmaf(RA.u2, yA2, gbs2)));
    out[3*rowB + 0] = fmaf(RB.a0, yB0, fmaf(RB.c0, yB1, fmaf(RB.u0, yB2, gbs0)));
    out[3*rowB + 1] = fmaf(RB.a1, yB0, fmaf(RB.c1, yB1, fmaf(RB.u1, yB2, gbs1)));
    out[3*rowB + 2] = fmaf(RB.a2, yB0, fmaf(RB.c2, yB1, fmaf(RB.u2, yB2, gbs2)));
}

extern "C" void kernel_launch(void* const* d_in, const int* in_sizes, int n_in,
                              void* d_out, int out_size, void* d_ws, size_t ws_size,
                              hipStream_t stream) {
    const float* v    = (const float*)d_in[0];
    const float* w    = (const float*)d_in[1];
    const float* W1   = (const float*)d_in[2];
    const float* b1   = (const float*)d_in[3];
    const float* W2   = (const float*)d_in[4];
    const float* b2   = (const float*)d_in[5];
    const float* Wd1  = (const float*)d_in[6];
    const float* bd1  = (const float*)d_in[7];
    const float* Wd2  = (const float*)d_in[8];
    const float* bd2  = (const float*)d_in[9];
    const float* bias = (const float*)d_in[10];

    const int nrows = in_sizes[0] / 3;
    dim3 block(256);
    dim3 grid((nrows + 511) / 512);
    hipLaunchKernelGGL(aero_mfma, grid, block, 0, stream,
                       v, w, W1, b1, W2, b2, Wd1, bd1, Wd2, bd2, bias,
                       (float*)d_out, nrows);
}